// Round 1
// baseline (188.006 us; speedup 1.0000x reference)
//
#include <hip/hip_runtime.h>
#include <hip/hip_bf16.h>

#define S_LEN 2048
#define DK 128
#define DV 128
#define BM 64    // Q rows per block (4 waves x 16)
#define BN 64    // KV rows per tile
#define LDK 136  // LDS K row stride in bf16 (128 + 8 pad, keeps 16B alignment)
#define LDV 72   // LDS Vt row stride in bf16 (64 + 8 pad)
#define LDP 72   // LDS P row stride in bf16

typedef __attribute__((ext_vector_type(8))) short s16x8;
typedef __attribute__((ext_vector_type(4))) short s16x4;
typedef __attribute__((ext_vector_type(8))) __bf16 bf16x8;
typedef __attribute__((ext_vector_type(4))) float f32x4;

// fp32 -> bf16 round-to-nearest-even (inputs are finite)
__device__ __forceinline__ short f2bf(float f) {
  unsigned u = __builtin_bit_cast(unsigned, f);
  u += 0x7FFFu + ((u >> 16) & 1u);
  return (short)(u >> 16);
}

__device__ __forceinline__ bf16x8 lds8(const short* p) {
  return __builtin_bit_cast(bf16x8, *(const s16x8*)p);
}

__global__ __launch_bounds__(256)
void fa_causal(const float* __restrict__ Q, const float* __restrict__ K,
               const float* __restrict__ V, float* __restrict__ Out) {
  __shared__ __align__(16) short lds_k[BN * LDK];     // 17408 B
  __shared__ __align__(16) short lds_vt[DV * LDV];    // 18432 B
  __shared__ __align__(16) short lds_p[4 * 16 * LDP]; //  9216 B

  const int b   = blockIdx.x >> 5;
  const int q0  = (blockIdx.x & 31) * BM;
  const int tid = threadIdx.x;
  const int wv  = tid >> 6;   // wave 0..3, handles Q rows [q0+wv*16, +16)
  const int ln  = tid & 63;
  const int c   = ln & 15;    // MFMA col / A-row lane index
  const int qd  = ln >> 4;    // quad 0..3

  const float scale2 = 0.12751741f; // log2(e) / sqrt(128): softmax in base-2 domain

  // ---- Q fragments: A-layout, lane holds Q[q0+wv*16+c][t*32 + qd*8 + j] ----
  bf16x8 qf[4];
  {
    const float* qrow = Q + ((size_t)(b * S_LEN + q0 + wv * 16 + c)) * DK + qd * 8;
#pragma unroll
    for (int t = 0; t < 4; ++t) {
      float4 x = *(const float4*)(qrow + t * 32);
      float4 y = *(const float4*)(qrow + t * 32 + 4);
      s16x8 f;
      f[0] = f2bf(x.x); f[1] = f2bf(x.y); f[2] = f2bf(x.z); f[3] = f2bf(x.w);
      f[4] = f2bf(y.x); f[5] = f2bf(y.y); f[6] = f2bf(y.z); f[7] = f2bf(y.w);
      qf[t] = __builtin_bit_cast(bf16x8, f);
    }
  }

  // O accumulator: C-layout, lane holds rows qd*4+r, cols cb2*16+c (8 col-blocks)
  f32x4 oacc[8];
#pragma unroll
  for (int i = 0; i < 8; ++i) oacc[i] = f32x4{0.f, 0.f, 0.f, 0.f};
  float mrow[4] = {-1e30f, -1e30f, -1e30f, -1e30f};
  float lrow[4] = {0.f, 0.f, 0.f, 0.f};

  const float* kbb = K + (size_t)b * S_LEN * DK;
  const float* vbb = V + (size_t)b * S_LEN * DV;
  short* pb = &lds_p[wv * 16 * LDP];

  for (int kv0 = 0; kv0 <= q0; kv0 += BN) {
    __syncthreads();  // prior iteration's PV reads done before restaging

    // ---- stage K tile [64][128] fp32->bf16, row-major ----
    {
      const float* kb = kbb + (size_t)kv0 * DK;
#pragma unroll
      for (int it = 0; it < 8; ++it) {
        int flat = it * 256 + tid;
        int r = flat >> 5, d4 = flat & 31;
        float4 x = *(const float4*)(kb + r * DK + d4 * 4);
        s16x4 s;
        s[0] = f2bf(x.x); s[1] = f2bf(x.y); s[2] = f2bf(x.z); s[3] = f2bf(x.w);
        *(s16x4*)&lds_k[r * LDK + d4 * 4] = s;
      }
      // ---- stage V tile transposed: lds_vt[d][kv_local] ----
      const float* vb = vbb + (size_t)kv0 * DV;
#pragma unroll
      for (int it = 0; it < 8; ++it) {
        int flat = it * 256 + tid;
        int d = flat & 127, r0 = (flat >> 7) << 2;
        s16x4 s;
        s[0] = f2bf(vb[(r0 + 0) * DV + d]);
        s[1] = f2bf(vb[(r0 + 1) * DV + d]);
        s[2] = f2bf(vb[(r0 + 2) * DV + d]);
        s[3] = f2bf(vb[(r0 + 3) * DV + d]);
        *(s16x4*)&lds_vt[d * LDV + r0] = s;
      }
    }
    __syncthreads();

    // ---- S = Q K^T for this wave's 16 rows x 64 cols ----
    f32x4 sc[4];
#pragma unroll
    for (int cb = 0; cb < 4; ++cb) {
      f32x4 acc = f32x4{0.f, 0.f, 0.f, 0.f};
      const short* kr = &lds_k[(cb * 16 + c) * LDK + qd * 8];
#pragma unroll
      for (int t = 0; t < 4; ++t)
        acc = __builtin_amdgcn_mfma_f32_16x16x32_bf16(qf[t], lds8(kr + t * 32), acc, 0, 0, 0);
      sc[cb] = acc;
    }

    // ---- scale (base-2) + causal mask (only diagonal tile needs it) ----
    if (kv0 == q0) {
#pragma unroll
      for (int cb = 0; cb < 4; ++cb)
#pragma unroll
        for (int r = 0; r < 4; ++r) {
          float s = sc[cb][r] * scale2;
          bool masked = (cb * 16 + c) > (wv * 16 + qd * 4 + r);
          sc[cb][r] = masked ? -1e30f : s;
        }
    } else {
#pragma unroll
      for (int cb = 0; cb < 4; ++cb)
#pragma unroll
        for (int r = 0; r < 4; ++r) sc[cb][r] *= scale2;
    }

    // ---- online softmax (rows qd*4+r, reduce across the 16 lanes of the quad-group) ----
    float tmax[4];
#pragma unroll
    for (int r = 0; r < 4; ++r)
      tmax[r] = fmaxf(fmaxf(sc[0][r], sc[1][r]), fmaxf(sc[2][r], sc[3][r]));
#pragma unroll
    for (int off = 1; off <= 8; off <<= 1)
#pragma unroll
      for (int r = 0; r < 4; ++r) tmax[r] = fmaxf(tmax[r], __shfl_xor(tmax[r], off));

    float al[4], tsum[4];
#pragma unroll
    for (int r = 0; r < 4; ++r) {
      float mn = fmaxf(mrow[r], tmax[r]);
      al[r] = __builtin_amdgcn_exp2f(mrow[r] - mn);
      mrow[r] = mn;
      tsum[r] = 0.f;
    }
    // P = exp2(S - m), write to per-wave LDS buffer (C-layout -> row-major)
#pragma unroll
    for (int cb = 0; cb < 4; ++cb)
#pragma unroll
      for (int r = 0; r < 4; ++r) {
        float p = __builtin_amdgcn_exp2f(sc[cb][r] - mrow[r]);
        tsum[r] += p;
        pb[(qd * 4 + r) * LDP + cb * 16 + c] = f2bf(p);
      }
#pragma unroll
    for (int off = 1; off <= 8; off <<= 1)
#pragma unroll
      for (int r = 0; r < 4; ++r) tsum[r] += __shfl_xor(tsum[r], off);
#pragma unroll
    for (int r = 0; r < 4; ++r) lrow[r] = lrow[r] * al[r] + tsum[r];
#pragma unroll
    for (int i = 0; i < 8; ++i)
#pragma unroll
      for (int r = 0; r < 4; ++r) oacc[i][r] *= al[r];

    __syncthreads();  // P visible to all lanes of the wave (cross-lane via LDS)

    // ---- O += P V : A = P (from LDS, A-layout), B = V (from transposed LDS) ----
#pragma unroll
    for (int t2 = 0; t2 < 2; ++t2) {
      bf16x8 pf = lds8(&pb[c * LDP + t2 * 32 + qd * 8]);
#pragma unroll
      for (int cb2 = 0; cb2 < 8; ++cb2) {
        bf16x8 vf = lds8(&lds_vt[(cb2 * 16 + c) * LDV + t2 * 32 + qd * 8]);
        oacc[cb2] = __builtin_amdgcn_mfma_f32_16x16x32_bf16(pf, vf, oacc[cb2], 0, 0, 0);
      }
    }
  }

  // ---- epilogue: divide by l, store fp32 ----
  float inv[4];
#pragma unroll
  for (int r = 0; r < 4; ++r) inv[r] = 1.0f / lrow[r];
  float* ob = Out + ((size_t)(b * S_LEN + q0 + wv * 16 + qd * 4)) * DV + c;
#pragma unroll
  for (int cb2 = 0; cb2 < 8; ++cb2)
#pragma unroll
    for (int r = 0; r < 4; ++r)
      ob[r * DV + cb2 * 16] = oacc[cb2][r] * inv[r];
}

extern "C" void kernel_launch(void* const* d_in, const int* in_sizes, int n_in,
                              void* d_out, int out_size, void* d_ws, size_t ws_size,
                              hipStream_t stream) {
  (void)in_sizes; (void)n_in; (void)out_size; (void)d_ws; (void)ws_size;
  const float* Q = (const float*)d_in[0];
  const float* K = (const float*)d_in[1];
  const float* V = (const float*)d_in[2];
  float* O = (float*)d_out;
  dim3 grid(16 * (S_LEN / BM));  // 512 blocks: batch * Q-tile
  fa_causal<<<grid, dim3(256), 0, stream>>>(Q, K, V, O);
}

// Round 2
// 163.420 us; speedup vs baseline: 1.1504x; 1.1504x over previous
//
#include <hip/hip_runtime.h>
#include <hip/hip_bf16.h>

#define S_LEN 2048
#define DK 128
#define DV 128
#define BM 64     // Q rows per block (4 waves x 16)
#define BN 64     // KV rows per tile
#define LDK 136   // LDS K row stride (bf16), 16B-aligned rows
#define LDV 72    // LDS Vt row stride (bf16)
#define LDP 72    // LDS P row stride (bf16)
#define CHUNK_T 8           // KV tiles per split-KV chunk (512 positions)
#define EPB 80              // chunks per batch: sum_{t=0..31} (t/8+1)
#define NBLK (16 * EPB)     // 1280 partial blocks
#define OPART_F ((size_t)NBLK * 8192)  // floats of O partials

typedef __attribute__((ext_vector_type(8))) short s16x8;
typedef __attribute__((ext_vector_type(4))) short s16x4;
typedef __attribute__((ext_vector_type(8))) __bf16 bf16x8;
typedef __attribute__((ext_vector_type(4))) float f32x4;

__device__ __forceinline__ short f2bf(float f) {
  unsigned u = __builtin_bit_cast(unsigned, f);
  u += 0x7FFFu + ((u >> 16) & 1u);
  return (short)(u >> 16);
}
__device__ __forceinline__ bf16x8 lds8(const short* p) {
  return __builtin_bit_cast(bf16x8, *(const s16x8*)p);
}

// Transposed-S flash attention. SPLIT=true: each block does one KV chunk of one
// Q-tile, writes unnormalized O + (m,l) partials to ws. SPLIT=false: full range,
// writes final output (fallback when ws too small).
template <bool SPLIT>
__global__ __launch_bounds__(256)
void fa_causal(const float* __restrict__ Q, const float* __restrict__ K,
               const float* __restrict__ V, float* __restrict__ Out,
               float* __restrict__ ws) {
  __shared__ __align__(16) short lds_k[BN * LDK];
  __shared__ __align__(16) short lds_vt[DV * LDV];
  __shared__ __align__(16) short lds_p[4 * 16 * LDP];

  const int bid = blockIdx.x;
  int b, t, ts, te;
  if (SPLIT) {
    b = bid / EPB;
    int e = bid % EPB, ch;
    if (e < 8)       { t = e;                       ch = 0; }
    else if (e < 24) { int u = e - 8;  t = 8 + (u >> 1);  ch = u & 1; }
    else if (e < 48) { int u = e - 24; t = 16 + u / 3;    ch = u - 3 * (t - 16); }
    else             { int u = e - 48; t = 24 + (u >> 2); ch = u & 3; }
    ts = ch * CHUNK_T;
    te = (ts + CHUNK_T < t + 1) ? ts + CHUNK_T : t + 1;
  } else {
    b = bid >> 5; t = bid & 31; ts = 0; te = t + 1;
  }
  const int q0  = t * BM;
  const int tid = threadIdx.x;
  const int wv  = tid >> 6;
  const int ln  = tid & 63;
  const int c   = ln & 15;   // = this lane's q-row (within wave's 16) and A-row index
  const int qd  = ln >> 4;

  const float scale2 = 0.12751741f;  // log2(e)/sqrt(128)
  const int qg = q0 + wv * 16 + c;   // global q row this lane owns

  // Q fragments: lane c holds Q[qg][t4*32 + qd*8 + j]  (A/B register format)
  bf16x8 qf[4];
  {
    const float* qrow = Q + (size_t)(b * S_LEN + qg) * DK + qd * 8;
#pragma unroll
    for (int t4 = 0; t4 < 4; ++t4) {
      float4 x = *(const float4*)(qrow + t4 * 32);
      float4 y = *(const float4*)(qrow + t4 * 32 + 4);
      s16x8 f;
      f[0] = f2bf(x.x); f[1] = f2bf(x.y); f[2] = f2bf(x.z); f[3] = f2bf(x.w);
      f[4] = f2bf(y.x); f[5] = f2bf(y.y); f[6] = f2bf(y.z); f[7] = f2bf(y.w);
      qf[t4] = __builtin_bit_cast(bf16x8, f);
    }
  }

  // O^T accumulator: lane holds O[q=c][d = cb2*16 + qd*4 + r]
  f32x4 oacc[8];
#pragma unroll
  for (int i = 0; i < 8; ++i) oacc[i] = f32x4{0.f, 0.f, 0.f, 0.f};
  float m_i = -1e30f, l_i = 0.f;

  const float* kbb = K + (size_t)b * S_LEN * DK;
  const float* vbb = V + (size_t)b * S_LEN * DV;
  short* pb = &lds_p[wv * 16 * LDP];

  for (int kt = ts; kt < te; ++kt) {
    const int kv0 = kt * BN;
    __syncthreads();  // prior iter's LDS reads done before restage

    {  // stage K tile [64][128] fp32->bf16 row-major
      const float* kb = kbb + (size_t)kv0 * DK;
#pragma unroll
      for (int it = 0; it < 8; ++it) {
        int flat = it * 256 + tid;
        int r = flat >> 5, d4 = flat & 31;
        float4 x = *(const float4*)(kb + r * DK + d4 * 4);
        s16x4 s;
        s[0] = f2bf(x.x); s[1] = f2bf(x.y); s[2] = f2bf(x.z); s[3] = f2bf(x.w);
        *(s16x4*)&lds_k[r * LDK + d4 * 4] = s;
      }
      // stage V transposed: lds_vt[d][kv_local]
      const float* vb = vbb + (size_t)kv0 * DV;
#pragma unroll
      for (int it = 0; it < 8; ++it) {
        int flat = it * 256 + tid;
        int d = flat & 127, r0 = (flat >> 7) << 2;
        s16x4 s;
        s[0] = f2bf(vb[(r0 + 0) * DV + d]);
        s[1] = f2bf(vb[(r0 + 1) * DV + d]);
        s[2] = f2bf(vb[(r0 + 2) * DV + d]);
        s[3] = f2bf(vb[(r0 + 3) * DV + d]);
        *(s16x4*)&lds_vt[d * LDV + r0] = s;
      }
    }
    __syncthreads();

    // S^T = K Q^T : lane holds S^T[kv = cb*16+qd*4+r][q = c]
    f32x4 st[4];
#pragma unroll
    for (int cb = 0; cb < 4; ++cb) {
      f32x4 acc = f32x4{0.f, 0.f, 0.f, 0.f};
      const short* kr = &lds_k[(cb * 16 + c) * LDK + qd * 8];
#pragma unroll
      for (int t4 = 0; t4 < 4; ++t4)
        acc = __builtin_amdgcn_mfma_f32_16x16x32_bf16(lds8(kr + t4 * 32), qf[t4], acc, 0, 0, 0);
      st[cb] = acc;
    }

    // scale + causal mask (diagonal tile only)
    if (kt == t) {
#pragma unroll
      for (int cb = 0; cb < 4; ++cb)
#pragma unroll
        for (int r = 0; r < 4; ++r) {
          bool masked = (kv0 + cb * 16 + qd * 4 + r) > qg;
          st[cb][r] = masked ? -1e30f : st[cb][r] * scale2;
        }
    } else {
#pragma unroll
      for (int cb = 0; cb < 4; ++cb)
#pragma unroll
        for (int r = 0; r < 4; ++r) st[cb][r] *= scale2;
    }

    // online softmax over kv (regs + lanes differing in qd bits)
    float tmax = -1e30f;
#pragma unroll
    for (int cb = 0; cb < 4; ++cb)
#pragma unroll
      for (int r = 0; r < 4; ++r) tmax = fmaxf(tmax, st[cb][r]);
    tmax = fmaxf(tmax, __shfl_xor(tmax, 16));
    tmax = fmaxf(tmax, __shfl_xor(tmax, 32));

    float mn = fmaxf(m_i, tmax);
    float al = __builtin_amdgcn_exp2f(m_i - mn);
    m_i = mn;
    float tsum = 0.f;
#pragma unroll
    for (int cb = 0; cb < 4; ++cb) {
      s16x4 pk;
#pragma unroll
      for (int r = 0; r < 4; ++r) {
        float p = __builtin_amdgcn_exp2f(st[cb][r] - m_i);
        tsum += p;
        pk[r] = f2bf(p);
      }
      // P stored [q=c][kv] row-major; lane's 4 values contiguous in kv -> b64
      *(s16x4*)&pb[c * LDP + cb * 16 + qd * 4] = pk;
    }
    tsum += __shfl_xor(tsum, 16);
    tsum += __shfl_xor(tsum, 32);
    l_i = l_i * al + tsum;
#pragma unroll
    for (int i = 0; i < 8; ++i)
#pragma unroll
      for (int r = 0; r < 4; ++r) oacc[i][r] *= al;

    // O^T += V^T P^T (P buffer is wave-private; lgkmcnt ordering suffices)
#pragma unroll
    for (int t2 = 0; t2 < 2; ++t2) {
      bf16x8 pf = lds8(&pb[c * LDP + t2 * 32 + qd * 8]);
#pragma unroll
      for (int cb2 = 0; cb2 < 8; ++cb2) {
        bf16x8 vf = lds8(&lds_vt[(cb2 * 16 + c) * LDV + t2 * 32 + qd * 8]);
        oacc[cb2] = __builtin_amdgcn_mfma_f32_16x16x32_bf16(vf, pf, oacc[cb2], 0, 0, 0);
      }
    }
  }

  if (SPLIT) {
    float* op = ws + (size_t)bid * 8192 + (wv * 16 + c) * 128;
#pragma unroll
    for (int cb2 = 0; cb2 < 8; ++cb2)
      *(f32x4*)(op + cb2 * 16 + qd * 4) = oacc[cb2];
    if (qd == 0) {
      float* wsm = ws + OPART_F;
      wsm[bid * 64 + wv * 16 + c] = m_i;
      wsm[NBLK * 64 + bid * 64 + wv * 16 + c] = l_i;
    }
  } else {
    float inv = 1.0f / l_i;
    float* ob = Out + (size_t)(b * S_LEN + qg) * DV;
#pragma unroll
    for (int cb2 = 0; cb2 < 8; ++cb2) {
      f32x4 v = oacc[cb2] * inv;
      *(f32x4*)(ob + cb2 * 16 + qd * 4) = v;
    }
  }
}

__global__ __launch_bounds__(256)
void fa_combine(const float* __restrict__ ws, float* __restrict__ Out) {
  const int bx = blockIdx.x;
  const int b = bx >> 5, t = bx & 31;
  const int nc = (t >> 3) + 1;
  const int cum = (t < 8) ? t : (t < 16) ? 8 + 2 * (t - 8)
                 : (t < 24) ? 24 + 3 * (t - 16) : 48 + 4 * (t - 24);
  const int bid0 = b * EPB + cum;
  const int tid = threadIdx.x;
  const int row = tid >> 2;          // 0..63
  const int dseg = (tid & 3) * 32;   // 0,32,64,96

  const float* wsm = ws + OPART_F;
  const float* wsl = wsm + (size_t)NBLK * 64;

  float mv[4], lv[4];
  float M = -1e30f;
  for (int cc = 0; cc < nc; ++cc) {
    mv[cc] = wsm[(bid0 + cc) * 64 + row];
    lv[cc] = wsl[(bid0 + cc) * 64 + row];
    M = fmaxf(M, mv[cc]);
  }
  float L = 0.f, w[4];
  for (int cc = 0; cc < nc; ++cc) {
    w[cc] = __builtin_amdgcn_exp2f(mv[cc] - M);
    L += lv[cc] * w[cc];
  }
  const float invL = 1.0f / L;

  f32x4 acc[8];
#pragma unroll
  for (int j = 0; j < 8; ++j) acc[j] = f32x4{0.f, 0.f, 0.f, 0.f};
  for (int cc = 0; cc < nc; ++cc) {
    const float* op = ws + (size_t)(bid0 + cc) * 8192 + row * 128 + dseg;
    const float wc = w[cc];
#pragma unroll
    for (int j = 0; j < 8; ++j) {
      f32x4 x = *(const f32x4*)(op + j * 4);
      acc[j] += x * wc;
    }
  }
  float* ob = Out + (size_t)(b * S_LEN + t * 64 + row) * DV + dseg;
#pragma unroll
  for (int j = 0; j < 8; ++j)
    *(f32x4*)(ob + j * 4) = acc[j] * invL;
}

extern "C" void kernel_launch(void* const* d_in, const int* in_sizes, int n_in,
                              void* d_out, int out_size, void* d_ws, size_t ws_size,
                              hipStream_t stream) {
  (void)in_sizes; (void)n_in; (void)out_size;
  const float* Q = (const float*)d_in[0];
  const float* K = (const float*)d_in[1];
  const float* V = (const float*)d_in[2];
  float* O = (float*)d_out;
  const size_t need = (OPART_F + 2 * (size_t)NBLK * 64) * sizeof(float);
  if (ws_size >= need) {
    fa_causal<true><<<dim3(NBLK), dim3(256), 0, stream>>>(Q, K, V, nullptr, (float*)d_ws);
    fa_combine<<<dim3(16 * 32), dim3(256), 0, stream>>>((const float*)d_ws, O);
  } else {
    fa_causal<false><<<dim3(16 * 32), dim3(256), 0, stream>>>(Q, K, V, O, nullptr);
  }
}

// Round 3
// 147.594 us; speedup vs baseline: 1.2738x; 1.1072x over previous
//
#include <hip/hip_runtime.h>
#include <hip/hip_bf16.h>

#define S_LEN 2048
#define DK 128
#define DV 128
#define BM 64     // Q rows per block (4 waves x 16)
#define BN 64     // KV rows per tile
#define NT 32     // KV tiles per batch
#define LDP 72    // LDS P row stride (bf16)
#define TILE_B 16384                        // bytes per staged tile (64x128 bf16)
#define VWS_OFF ((size_t)16 * NT * TILE_B)  // 8.39 MB
#define WS_NEED ((size_t)2 * 16 * NT * TILE_B)

typedef __attribute__((ext_vector_type(8))) short s16x8;
typedef __attribute__((ext_vector_type(4))) short s16x4;
typedef __attribute__((ext_vector_type(8))) __bf16 bf16x8;
typedef __attribute__((ext_vector_type(4))) float f32x4;

__device__ __forceinline__ short f2bf(float f) {
  unsigned u = __builtin_bit_cast(unsigned, f);
  u += 0x7FFFu + ((u >> 16) & 1u);
  return (short)(u >> 16);
}
__device__ __forceinline__ bf16x8 lds8(const short* p) {
  return __builtin_bit_cast(bf16x8, *(const s16x8*)p);
}
// async global->LDS, 16B per lane; LDS dest = wave-uniform base + lane*16
__device__ __forceinline__ void gload16(const void* g, void* l) {
  __builtin_amdgcn_global_load_lds(
      (const __attribute__((address_space(1))) void*)g,
      (__attribute__((address_space(3))) void*)l, 16, 0, 0);
}

// ---------------------------------------------------------------------------
// Pass 1: convert K -> bf16 and V -> bf16-transposed, tile-major, chunks
// pre-permuted in the main kernel's XOR-swizzled LDS order, so staging is a
// raw byte copy via global_load_lds.
//   K tile:  chunk(r in[0,64), cix in[0,16)) = K[kv0+r][cix*8 .. +8)
//            stored at chunk position r*16 + (cix ^ (r&7))
//   Vt tile: chunk(d in[0,128), cix in[0,8)) = V[kv0+cix*8 .. +8][d] (transposed)
//            stored at chunk position d*8 + (cix ^ (d&7))
// ---------------------------------------------------------------------------
__global__ __launch_bounds__(256)
void fa_convert(const float* __restrict__ K, const float* __restrict__ V,
                char* __restrict__ ws) {
  const int bid = blockIdx.x;
  const int tid = threadIdx.x;
  if (bid < 512) {  // K: bid = b*32 + kt
    const int b = bid >> 5, kt = bid & 31;
    const float* kb = K + (size_t)(b * S_LEN + kt * BN) * DK;
    short* out = (short*)(ws + (size_t)bid * TILE_B);
#pragma unroll
    for (int it = 0; it < 4; ++it) {
      int o = it * 256 + tid;
      int r = o >> 4, cix = o & 15;
      const float* src = kb + r * DK + cix * 8;
      float4 x = *(const float4*)src;
      float4 y = *(const float4*)(src + 4);
      s16x8 f;
      f[0] = f2bf(x.x); f[1] = f2bf(x.y); f[2] = f2bf(x.z); f[3] = f2bf(x.w);
      f[4] = f2bf(y.x); f[5] = f2bf(y.y); f[6] = f2bf(y.z); f[7] = f2bf(y.w);
      int pos = r * 16 + (cix ^ (r & 7));
      *(s16x8*)(out + pos * 8) = f;
    }
  } else {  // V transpose: vb = b*32 + kt
    const int vb = bid - 512;
    const int b = vb >> 5, kt = vb & 31;
    const float* vbase = V + (size_t)(b * S_LEN + kt * BN) * DV;
    short* out = (short*)(ws + VWS_OFF + (size_t)vb * TILE_B);
#pragma unroll
    for (int it = 0; it < 4; ++it) {
      int o = it * 256 + tid;
      int d = o >> 3, cix = o & 7;
      s16x8 f;
#pragma unroll
      for (int j = 0; j < 8; ++j)
        f[j] = f2bf(vbase[(cix * 8 + j) * DV + d]);
      int pos = d * 8 + (cix ^ (d & 7));
      *(s16x8*)(out + pos * 8) = f;
    }
  }
}

// ---------------------------------------------------------------------------
// Pass 2: transposed-S flash attention, K/Vt staged via global_load_lds.
// Block = 64 Q rows (4 waves x 16). Heavy/light tile pairing balances the
// causal triangle without split-KV: bid<256 -> t in [16,32), else t in [0,16),
// so under round-robin dispatch each CU gets one heavy + one light block.
// ---------------------------------------------------------------------------
__global__ __launch_bounds__(256)
void fa_main(const float* __restrict__ Q, const char* __restrict__ ws,
             float* __restrict__ Out) {
  __shared__ __align__(16) short lds_k[BN * DK];   // 16384 B, swizzled chunks
  __shared__ __align__(16) short lds_vt[DV * BN];  // 16384 B, swizzled chunks
  __shared__ __align__(16) short lds_p[4 * 16 * LDP];

  const int bid = blockIdx.x;
  int b, t;
  if (bid < 256) { b = bid >> 4; t = 16 + (bid & 15); }
  else           { int u = bid - 256; b = u >> 4; t = u & 15; }
  const int q0  = t * BM;
  const int tid = threadIdx.x;
  const int wv  = tid >> 6, ln = tid & 63;
  const int c   = ln & 15, qd = ln >> 4;
  const int s3  = c & 7;                 // xor key: row&7 == c&7 for our reads
  const float scale2 = 0.12751741f;      // log2(e)/sqrt(128), folded into Q
  const int qg = q0 + wv * 16 + c;

  // Q fragments, pre-scaled: lane c holds Q[qg][t4*32 + qd*8 + j] * scale2
  bf16x8 qf[4];
  {
    const float* qrow = Q + (size_t)(b * S_LEN + qg) * DK + qd * 8;
#pragma unroll
    for (int t4 = 0; t4 < 4; ++t4) {
      float4 x = *(const float4*)(qrow + t4 * 32);
      float4 y = *(const float4*)(qrow + t4 * 32 + 4);
      s16x8 f;
      f[0] = f2bf(x.x * scale2); f[1] = f2bf(x.y * scale2);
      f[2] = f2bf(x.z * scale2); f[3] = f2bf(x.w * scale2);
      f[4] = f2bf(y.x * scale2); f[5] = f2bf(y.y * scale2);
      f[6] = f2bf(y.z * scale2); f[7] = f2bf(y.w * scale2);
      qf[t4] = __builtin_bit_cast(bf16x8, f);
    }
  }

  // step-invariant swizzled LDS read offsets (element units)
  int koff[4][4], voff[8][2];
#pragma unroll
  for (int cb = 0; cb < 4; ++cb)
#pragma unroll
    for (int t4 = 0; t4 < 4; ++t4)
      koff[cb][t4] = ((cb * 16 + c) * 16 + ((qd + 4 * t4) ^ s3)) * 8;
#pragma unroll
  for (int cb2 = 0; cb2 < 8; ++cb2)
#pragma unroll
    for (int t2 = 0; t2 < 2; ++t2)
      voff[cb2][t2] = ((cb2 * 16 + c) * 8 + ((qd + 4 * t2) ^ s3)) * 8;

  f32x4 oacc[8];
#pragma unroll
  for (int i = 0; i < 8; ++i) oacc[i] = f32x4{0.f, 0.f, 0.f, 0.f};
  float m_i = -1e30f, l_i = 0.f;

  short* pb = &lds_p[wv * 16 * LDP];
  const char* kg = ws + (size_t)(b * NT) * TILE_B + wv * 4096 + ln * 16;
  const char* vg = ws + VWS_OFF + (size_t)(b * NT) * TILE_B + wv * 4096 + ln * 16;
  char* lk = (char*)lds_k + wv * 4096;
  char* lv = (char*)lds_vt + wv * 4096;

  for (int kt = 0; kt <= t; ++kt) {
    __syncthreads();  // prior step's LDS reads done before restage
#pragma unroll
    for (int i = 0; i < 4; ++i) {
      gload16(kg + i * 1024, lk + i * 1024);
      gload16(vg + i * 1024, lv + i * 1024);
    }
    kg += TILE_B; vg += TILE_B;
    __syncthreads();  // drains vmcnt(0): staged data visible

    // S^T = K Q^T : lane holds S^T[kv = cb*16+qd*4+r][q = c] (pre-scaled, base-2)
    f32x4 st[4];
#pragma unroll
    for (int cb = 0; cb < 4; ++cb) {
      f32x4 acc = f32x4{0.f, 0.f, 0.f, 0.f};
#pragma unroll
      for (int t4 = 0; t4 < 4; ++t4)
        acc = __builtin_amdgcn_mfma_f32_16x16x32_bf16(
            lds8(&lds_k[koff[cb][t4]]), qf[t4], acc, 0, 0, 0);
      st[cb] = acc;
    }

    // causal mask, diagonal tile only
    if (kt == t) {
#pragma unroll
      for (int cb = 0; cb < 4; ++cb)
#pragma unroll
        for (int r = 0; r < 4; ++r)
          if (cb * 16 + qd * 4 + r > wv * 16 + c) st[cb][r] = -1e30f;
    }

    // online softmax over kv (16 regs + lanes differing in qd bits)
    float tmax = -1e30f;
#pragma unroll
    for (int cb = 0; cb < 4; ++cb)
#pragma unroll
      for (int r = 0; r < 4; ++r) tmax = fmaxf(tmax, st[cb][r]);
    tmax = fmaxf(tmax, __shfl_xor(tmax, 16));
    tmax = fmaxf(tmax, __shfl_xor(tmax, 32));

    float mn = fmaxf(m_i, tmax);
    float al = __builtin_amdgcn_exp2f(m_i - mn);
    m_i = mn;
    float tsum = 0.f;
#pragma unroll
    for (int cb = 0; cb < 4; ++cb) {
      s16x4 pk;
#pragma unroll
      for (int r = 0; r < 4; ++r) {
        float p = __builtin_amdgcn_exp2f(st[cb][r] - m_i);
        tsum += p;
        pk[r] = f2bf(p);
      }
      *(s16x4*)&pb[c * LDP + cb * 16 + qd * 4] = pk;  // P[q=c][kv], b64
    }
    tsum += __shfl_xor(tsum, 16);
    tsum += __shfl_xor(tsum, 32);
    l_i = l_i * al + tsum;
#pragma unroll
    for (int i = 0; i < 8; ++i)
#pragma unroll
      for (int r = 0; r < 4; ++r) oacc[i][r] *= al;

    // O^T += V^T P^T  (P is wave-private: wave-lockstep + lgkmcnt suffice)
#pragma unroll
    for (int t2 = 0; t2 < 2; ++t2) {
      bf16x8 pf = lds8(&pb[c * LDP + t2 * 32 + qd * 8]);
#pragma unroll
      for (int cb2 = 0; cb2 < 8; ++cb2) {
        bf16x8 vf = lds8(&lds_vt[voff[cb2][t2]]);
        oacc[cb2] = __builtin_amdgcn_mfma_f32_16x16x32_bf16(vf, pf, oacc[cb2], 0, 0, 0);
      }
    }
  }

  // epilogue: normalize, store fp32 (lane holds O[q=c][d=cb2*16+qd*4+r])
  float inv = 1.0f / l_i;
  float* ob = Out + (size_t)(b * S_LEN + qg) * DV;
#pragma unroll
  for (int cb2 = 0; cb2 < 8; ++cb2) {
    f32x4 v = oacc[cb2] * inv;
    *(f32x4*)(ob + cb2 * 16 + qd * 4) = v;
  }
}

// ---------------------------------------------------------------------------
// Fallback (ws too small): R2's verified single-pass kernel, in-kernel convert.
// ---------------------------------------------------------------------------
__global__ __launch_bounds__(256)
void fa_fallback(const float* __restrict__ Q, const float* __restrict__ K,
                 const float* __restrict__ V, float* __restrict__ Out) {
  __shared__ __align__(16) short lds_k[BN * 136];
  __shared__ __align__(16) short lds_vt[DV * 72];
  __shared__ __align__(16) short lds_p[4 * 16 * LDP];

  const int bid = blockIdx.x;
  const int b = bid >> 5, t = bid & 31;
  const int q0 = t * BM;
  const int tid = threadIdx.x;
  const int wv = tid >> 6, ln = tid & 63;
  const int c = ln & 15, qd = ln >> 4;
  const float scale2 = 0.12751741f;
  const int qg = q0 + wv * 16 + c;

  bf16x8 qf[4];
  {
    const float* qrow = Q + (size_t)(b * S_LEN + qg) * DK + qd * 8;
#pragma unroll
    for (int t4 = 0; t4 < 4; ++t4) {
      float4 x = *(const float4*)(qrow + t4 * 32);
      float4 y = *(const float4*)(qrow + t4 * 32 + 4);
      s16x8 f;
      f[0] = f2bf(x.x * scale2); f[1] = f2bf(x.y * scale2);
      f[2] = f2bf(x.z * scale2); f[3] = f2bf(x.w * scale2);
      f[4] = f2bf(y.x * scale2); f[5] = f2bf(y.y * scale2);
      f[6] = f2bf(y.z * scale2); f[7] = f2bf(y.w * scale2);
      qf[t4] = __builtin_bit_cast(bf16x8, f);
    }
  }
  f32x4 oacc[8];
#pragma unroll
  for (int i = 0; i < 8; ++i) oacc[i] = f32x4{0.f, 0.f, 0.f, 0.f};
  float m_i = -1e30f, l_i = 0.f;
  const float* kbb = K + (size_t)b * S_LEN * DK;
  const float* vbb = V + (size_t)b * S_LEN * DV;
  short* pb = &lds_p[wv * 16 * LDP];

  for (int kt = 0; kt <= t; ++kt) {
    const int kv0 = kt * BN;
    __syncthreads();
    {
      const float* kb = kbb + (size_t)kv0 * DK;
#pragma unroll
      for (int it = 0; it < 8; ++it) {
        int flat = it * 256 + tid;
        int r = flat >> 5, d4 = flat & 31;
        float4 x = *(const float4*)(kb + r * DK + d4 * 4);
        s16x4 s;
        s[0] = f2bf(x.x); s[1] = f2bf(x.y); s[2] = f2bf(x.z); s[3] = f2bf(x.w);
        *(s16x4*)&lds_k[r * 136 + d4 * 4] = s;
      }
      const float* vb = vbb + (size_t)kv0 * DV;
#pragma unroll
      for (int it = 0; it < 8; ++it) {
        int flat = it * 256 + tid;
        int d = flat & 127, r0 = (flat >> 7) << 2;
        s16x4 s;
        s[0] = f2bf(vb[(r0 + 0) * DV + d]);
        s[1] = f2bf(vb[(r0 + 1) * DV + d]);
        s[2] = f2bf(vb[(r0 + 2) * DV + d]);
        s[3] = f2bf(vb[(r0 + 3) * DV + d]);
        *(s16x4*)&lds_vt[d * 72 + r0] = s;
      }
    }
    __syncthreads();
    f32x4 st[4];
#pragma unroll
    for (int cb = 0; cb < 4; ++cb) {
      f32x4 acc = f32x4{0.f, 0.f, 0.f, 0.f};
      const short* kr = &lds_k[(cb * 16 + c) * 136 + qd * 8];
#pragma unroll
      for (int t4 = 0; t4 < 4; ++t4)
        acc = __builtin_amdgcn_mfma_f32_16x16x32_bf16(lds8(kr + t4 * 32), qf[t4], acc, 0, 0, 0);
      st[cb] = acc;
    }
    if (kt == t) {
#pragma unroll
      for (int cb = 0; cb < 4; ++cb)
#pragma unroll
        for (int r = 0; r < 4; ++r)
          if (cb * 16 + qd * 4 + r > wv * 16 + c) st[cb][r] = -1e30f;
    }
    float tmax = -1e30f;
#pragma unroll
    for (int cb = 0; cb < 4; ++cb)
#pragma unroll
      for (int r = 0; r < 4; ++r) tmax = fmaxf(tmax, st[cb][r]);
    tmax = fmaxf(tmax, __shfl_xor(tmax, 16));
    tmax = fmaxf(tmax, __shfl_xor(tmax, 32));
    float mn = fmaxf(m_i, tmax);
    float al = __builtin_amdgcn_exp2f(m_i - mn);
    m_i = mn;
    float tsum = 0.f;
#pragma unroll
    for (int cb = 0; cb < 4; ++cb) {
      s16x4 pk;
#pragma unroll
      for (int r = 0; r < 4; ++r) {
        float p = __builtin_amdgcn_exp2f(st[cb][r] - m_i);
        tsum += p;
        pk[r] = f2bf(p);
      }
      *(s16x4*)&pb[c * LDP + cb * 16 + qd * 4] = pk;
    }
    tsum += __shfl_xor(tsum, 16);
    tsum += __shfl_xor(tsum, 32);
    l_i = l_i * al + tsum;
#pragma unroll
    for (int i = 0; i < 8; ++i)
#pragma unroll
      for (int r = 0; r < 4; ++r) oacc[i][r] *= al;
#pragma unroll
    for (int t2 = 0; t2 < 2; ++t2) {
      bf16x8 pf = lds8(&pb[c * LDP + t2 * 32 + qd * 8]);
#pragma unroll
      for (int cb2 = 0; cb2 < 8; ++cb2) {
        bf16x8 vf = lds8(&lds_vt[(cb2 * 16 + c) * 72 + t2 * 32 + qd * 8]);
        oacc[cb2] = __builtin_amdgcn_mfma_f32_16x16x32_bf16(vf, pf, oacc[cb2], 0, 0, 0);
      }
    }
  }
  float inv = 1.0f / l_i;
  float* ob = Out + (size_t)(b * S_LEN + qg) * DV;
#pragma unroll
  for (int cb2 = 0; cb2 < 8; ++cb2) {
    f32x4 v = oacc[cb2] * inv;
    *(f32x4*)(ob + cb2 * 16 + qd * 4) = v;
  }
}

extern "C" void kernel_launch(void* const* d_in, const int* in_sizes, int n_in,
                              void* d_out, int out_size, void* d_ws, size_t ws_size,
                              hipStream_t stream) {
  (void)in_sizes; (void)n_in; (void)out_size;
  const float* Q = (const float*)d_in[0];
  const float* K = (const float*)d_in[1];
  const float* V = (const float*)d_in[2];
  float* O = (float*)d_out;
  if (ws_size >= WS_NEED) {
    fa_convert<<<dim3(1024), dim3(256), 0, stream>>>(K, V, (char*)d_ws);
    fa_main<<<dim3(512), dim3(256), 0, stream>>>(Q, (const char*)d_ws, O);
  } else {
    fa_fallback<<<dim3(512), dim3(256), 0, stream>>>(Q, K, V, O);
  }
}